// Round 12
// baseline (251.803 us; speedup 1.0000x reference)
//
#include <hip/hip_runtime.h>
#include <math.h>

#define NI 128
#define NC 256
#define NR 36
#define NW 48
#define ND 256

#define PIB 264      // sIb pitch (bf16): 528 B rows, 16B-aligned
#define PG  64       // sG pitch: cols 36..63 zeroed (k-pad for phase-2 pa1 overread)
#define PSP 40       // sP pitch: cols 36..39 zero; col 40..63 overreads hit finite data x sG zeros

// lambda_softmax(9) * log2(e); lambda_lse(6) * log2(e)
#define SOFT_SCALE 12.984255368000671f
#define LSE_SCALE   8.656170245333781f

typedef __bf16 bf16;
typedef __bf16 bf16x8 __attribute__((ext_vector_type(8)));
typedef __bf16 bf16x4 __attribute__((ext_vector_type(4)));
typedef float  f32x4  __attribute__((ext_vector_type(4)));

// LDS carve (bytes) — 39104 total -> 4 blocks/CU
#define OFF_IB    0        // 36*264*2 = 19008 (no pad rows: overlapped tiles {0,16,20})
#define OFF_G     19008    // 36*64*2  = 4608  -> 23616
#define OFF_P     23616    // 4 wave-private: 4*48*40*2 = 15360 -> 38976
#define OFF_GUARD 38976    // 128 B zero tail (sP row-47 pa1 overread)
#define SMEM_TOTAL 39104

#define MFMA16(A,B,C) __builtin_amdgcn_mfma_f32_16x16x32_bf16(A, B, C, 0, 0, 0)

__device__ __forceinline__ float dpp_add16(float v) {
    int x = __builtin_bit_cast(int, v);
    v += __builtin_bit_cast(float, __builtin_amdgcn_update_dpp(0, x, 0xB1, 0xF, 0xF, true));
    x = __builtin_bit_cast(int, v);
    v += __builtin_bit_cast(float, __builtin_amdgcn_update_dpp(0, x, 0x4E, 0xF, 0xF, true));
    x = __builtin_bit_cast(int, v);
    v += __builtin_bit_cast(float, __builtin_amdgcn_update_dpp(0, x, 0x141, 0xF, 0xF, true));
    x = __builtin_bit_cast(int, v);
    v += __builtin_bit_cast(float, __builtin_amdgcn_update_dpp(0, x, 0x140, 0xF, 0xF, true));
    return v;
}

__device__ __forceinline__ float lrelu(float t) { return t > 0.f ? t : 0.1f * t; }

// fp32 load + inline bf16 convert + fp32 norm accumulation (replaces prep kernel:
// two-kernel graph cost ~30 µs launch serialization > ~13 µs inline cvt cost)
__device__ __forceinline__ bf16x8 ld_cvt_f32(const float* p, float& ss) {
    float4 lo = *(const float4*)p;
    float4 hi = *(const float4*)(p + 4);
    ss += lo.x*lo.x + lo.y*lo.y + lo.z*lo.z + lo.w*lo.w
        + hi.x*hi.x + hi.y*hi.y + hi.z*hi.z + hi.w*hi.w;
    bf16x8 r = { (bf16)lo.x, (bf16)lo.y, (bf16)lo.z, (bf16)lo.w,
                 (bf16)hi.x, (bf16)hi.y, (bf16)hi.z, (bf16)hi.w };
    return r;
}

// gfx950 unified VGPR/AGPR file: waves_per_eu(4,4) => 128-reg TOTAL budget.
// Demand ~115-120 (w1 kept as 3-reg ssc[], re-broadcast per-mt via shfl;
// Gram B-frags reloaded from LDS per-mt). WRITE_SIZE is the spill canary.
__global__ __attribute__((amdgpu_flat_work_group_size(256, 256), amdgpu_waves_per_eu(4, 4)))
void scan_kernel(const float* __restrict__ images,
                 const float* __restrict__ captions,
                 float* __restrict__ out)
{
    __shared__ __align__(16) unsigned char smem[SMEM_TOTAL];
    bf16* sIb = (bf16*)(smem + OFF_IB);   // [r][d] image, 36 real rows only
    bf16* sG  = (bf16*)(smem + OFF_G);    // [r'][r] Gram, 36 rows x 64 cols (36..63 zero)

    const int tid  = threadIdx.x;
    const int wave = tid >> 6;
    const int lane = tid & 63;
    const int quad = lane >> 4;
    const int l15  = lane & 15;
    const int i    = blockIdx.x >> 3;
    const int c0   = (blockIdx.x & 7) * 32;   // chunk == blockIdx%8 -> XCD-pinned captions

    bf16* sPw = (bf16*)(smem + OFF_P) + wave * (48 * PSP);

    // r-tile bases: {0,16,20} — tile 2 overlaps tile 1 on r=20..31; real rows only
    const int rb2 = 20;

    // ---- init: stage image bf16, zero sG and sP+guard ----
    const float* gI = images + (size_t)i * NR * ND;
    #pragma unroll
    for (int k = 0; k < 9; ++k) {
        int t = tid + k * 256;               // 2304 float4
        int e = t * 4, r = e >> 8, d = e & 255;
        float4 v = *(const float4*)(gI + e);
        bf16x4 h = { (bf16)v.x, (bf16)v.y, (bf16)v.z, (bf16)v.w };
        *(bf16x4*)&sIb[r * PIB + d] = h;
    }
    {
        uint32_t* pG = (uint32_t*)sG;        // 1152 dwords
        #pragma unroll
        for (int k = 0; k < 5; ++k) { int x = tid + k * 256; if (x < 1152) pG[x] = 0u; }
        uint32_t* pP = (uint32_t*)(smem + OFF_P);   // sP + guard: 3904 dwords
        #pragma unroll
        for (int k = 0; k < 16; ++k) { int x = tid + k * 256; if (x < 3904) pP[x] = 0u; }
    }
    __syncthreads();   // B0

    // ---- once: Gram G = I*I^T over overlapped m-tiles {0,16,20} (waves 0-2) ----
    if (wave < 3) {
        const int mb = (wave == 2) ? rb2 : wave * 16;
        f32x4 g0 = {0,0,0,0}, g1 = {0,0,0,0}, g2 = {0,0,0,0};
        #pragma unroll
        for (int ks = 0; ks < 8; ++ks) {
            bf16x8 a  = *(const bf16x8*)&sIb[(mb + l15)  * PIB + ks * 32 + quad * 8];
            bf16x8 b0 = *(const bf16x8*)&sIb[(l15)       * PIB + ks * 32 + quad * 8];
            bf16x8 b1 = *(const bf16x8*)&sIb[(16 + l15)  * PIB + ks * 32 + quad * 8];
            bf16x8 b2 = *(const bf16x8*)&sIb[(rb2 + l15) * PIB + ks * 32 + quad * 8];
            g0 = MFMA16(a, b0, g0); g1 = MFMA16(a, b1, g1); g2 = MFMA16(a, b2, g2);
        }
        // duplicate writes in overlap regions carry identical values (benign)
        #pragma unroll
        for (int p = 0; p < 4; ++p) {
            int m = mb + quad * 4 + p;
            sG[m * PG + l15]       = (bf16)g0[p];
            sG[m * PG + 16 + l15]  = (bf16)g1[p];
            sG[m * PG + rb2 + l15] = (bf16)g2[p];
        }
    }
    __syncthreads();   // B1: sG published. No further barriers.

    // ---- per-wave: 8 captions, everything in-wave ----
    for (int it = 0; it < 8; ++it) {
        const int c = c0 + wave * 8 + it;

        // ---- phase 1: raw logits attnT[w][r] = C_c · I^T, fp32 A + inline cvt ----
        f32x4 acc[3][3] = {};
        float ssc[3] = {0.f, 0.f, 0.f};
        const float* ab32 = captions + ((size_t)c * NW + l15) * ND + quad * 8;
        #pragma unroll
        for (int ks = 0; ks < 8; ++ks) {
            bf16x8 a0 = ld_cvt_f32(ab32 + ks * 32, ssc[0]);
            bf16x8 a1 = ld_cvt_f32(ab32 + 16 * ND + ks * 32, ssc[1]);
            bf16x8 a2 = ld_cvt_f32(ab32 + 32 * ND + ks * 32, ssc[2]);
            bf16x8 b0 = *(const bf16x8*)&sIb[(l15)       * PIB + ks * 32 + quad * 8];
            bf16x8 b1 = *(const bf16x8*)&sIb[(16 + l15)  * PIB + ks * 32 + quad * 8];
            bf16x8 b2 = *(const bf16x8*)&sIb[(rb2 + l15) * PIB + ks * 32 + quad * 8];
            acc[0][0] = MFMA16(a0, b0, acc[0][0]);
            acc[1][0] = MFMA16(a1, b0, acc[1][0]);
            acc[2][0] = MFMA16(a2, b0, acc[2][0]);
            acc[0][1] = MFMA16(a0, b1, acc[0][1]);
            acc[1][1] = MFMA16(a1, b1, acc[1][1]);
            acc[2][1] = MFMA16(a2, b1, acc[2][1]);
            acc[0][2] = MFMA16(a0, b2, acc[0][2]);
            acc[1][2] = MFMA16(a1, b2, acc[1][2]);
            acc[2][2] = MFMA16(a2, b2, acc[2][2]);
        }
        // caption row norms: reduce over quads; ssc[mt] = w1 of row mt*16+l15 (3 regs only)
        #pragma unroll
        for (int mt = 0; mt < 3; ++mt) {
            float s = ssc[mt];
            s += __shfl_xor(s, 16); s += __shfl_xor(s, 32);
            ssc[mt] = sqrtf(s);
        }

        // ---- l2norm over w; nt=2 valid at l15>=12 (r=32..35); fold 9*log2e ----
        float inv[3];
        #pragma unroll
        for (int nt = 0; nt < 3; ++nt) {
            float s = 0.f;
            #pragma unroll
            for (int mt = 0; mt < 3; ++mt)
                #pragma unroll
                for (int p = 0; p < 4; ++p) { float t = lrelu(acc[mt][nt][p]); s += t * t; }
            s += __shfl_xor(s, 16); s += __shfl_xor(s, 32);       // sum over w-quads
            inv[nt] = SOFT_SCALE / (sqrtf(s) + 1e-8f);
        }

        // ---- per-mt fused: un-normalized softmax -> sP -> eG MFMA -> w2/rsim/LSE ----
        float esum = 0.f;
        #pragma unroll
        for (int mt = 0; mt < 3; ++mt) {
            float q0[4], q1[4], q2[4], w12v[4];
            #pragma unroll
            for (int p = 0; p < 4; ++p) {
                float e0 = exp2f(lrelu(acc[mt][0][p]) * inv[0]);
                float e1 = exp2f(lrelu(acc[mt][1][p]) * inv[1]);
                float e2 = (l15 >= 12) ? exp2f(lrelu(acc[mt][2][p]) * inv[2]) : 0.f;  // r=32..35
                w12v[p] = dpp_add16(e0 * acc[mt][0][p] + e1 * acc[mt][1][p]
                                   + e2 * acc[mt][2][p]);
                q0[p] = e0; q1[p] = e1; q2[p] = e2;
                int row = mt * 16 + quad * 4 + p;
                sPw[row * PSP + l15]      = (bf16)e0;
                sPw[row * PSP + 16 + l15] = (bf16)e1;
                if (l15 >= 12) sPw[row * PSP + rb2 + l15] = (bf16)e2;   // cols 32..35
            }
            // same-wave RAW on sPw (compiler lgkmcnt); no barrier
            const bf16* ap = &sPw[(mt * 16 + l15) * PSP];
            bf16x8 pa0 = *(const bf16x8*)(ap + quad * 8);
            bf16x8 pa1 = *(const bf16x8*)(ap + 32 + quad * 8);   // overread: finite x sG zeros
            // Gram B-frags reloaded per mt (no hoist: register budget)
            f32x4 pg0 = {0,0,0,0}, pg1 = {0,0,0,0}, pg2 = {0,0,0,0};
            {
                bf16x8 t0 = *(const bf16x8*)&sG[(l15) * PG + quad * 8];
                bf16x8 t1 = *(const bf16x8*)&sG[(l15) * PG + 32 + quad * 8];
                pg0 = MFMA16(pa0, t0, pg0); pg0 = MFMA16(pa1, t1, pg0);
                bf16x8 t2 = *(const bf16x8*)&sG[(16 + l15) * PG + quad * 8];
                bf16x8 t3 = *(const bf16x8*)&sG[(16 + l15) * PG + 32 + quad * 8];
                pg1 = MFMA16(pa0, t2, pg1); pg1 = MFMA16(pa1, t3, pg1);
                bf16x8 t4 = *(const bf16x8*)&sG[(rb2 + l15) * PG + quad * 8];
                bf16x8 t5 = *(const bf16x8*)&sG[(rb2 + l15) * PG + 32 + quad * 8];
                pg2 = MFMA16(pa0, t4, pg2); pg2 = MFMA16(pa1, t5, pg2);
            }
            #pragma unroll
            for (int p = 0; p < 4; ++p) {
                float s2 = pg0[p] * q0[p] + pg1[p] * q1[p] + pg2[p] * q2[p];
                s2 = dpp_add16(s2);
                float w2v = sqrtf(fmaxf(s2, 0.f));
                // w1 for w = mt*16+quad*4+p: broadcast from the lane holding that row
                float w1x = __shfl(ssc[mt], (lane & 48) + quad * 4 + p);
                float rsim = w12v[p] / fmaxf(w1x * w2v, 1e-8f);
                esum += exp2f(LSE_SCALE * rsim);
            }
        }
        esum += __shfl_xor(esum, 16); esum += __shfl_xor(esum, 32);
        if (lane == 0) out[(size_t)i * NC + c] = logf(esum) * (1.0f / 6.0f);
    }
}

extern "C" void kernel_launch(void* const* d_in, const int* in_sizes, int n_in,
                              void* d_out, int out_size, void* d_ws, size_t ws_size,
                              hipStream_t stream) {
    const float* images   = (const float*)d_in[0];   // (128, 36, 256) fp32
    const float* captions = (const float*)d_in[1];   // (256, 48, 256) fp32
    float* out = (float*)d_out;                      // (128, 256) fp32

    dim3 grid(1024), block(256);   // 128 images x 8 XCD-pinned chunks; 4 blocks/CU target
    hipLaunchKernelGGL(scan_kernel, grid, block, 0, stream, images, captions, out);
}

// Round 13
// 173.796 us; speedup vs baseline: 1.4488x; 1.4488x over previous
//
#include <hip/hip_runtime.h>
#include <math.h>

#define NI 128
#define NC 256
#define NR 36
#define NW 48
#define ND 256

#define PIB 264      // sIb pitch (bf16): 528 B rows -> bank (4*l15+4q+j)%32, 2-way: free
#define PG  72       // sG pitch: 144 B rows, 2-way banks. (R11 used 64 = 128 B rows ->
                     // 16-way conflict on every per-mt sG b128 read: 1.15e7 conflict cycles)
#define PSP 40       // sP pitch: cols 36..39 zero; col 40..63 overreads hit finite data x sG zeros

// lambda_softmax(9) * log2(e); lambda_lse(6) * log2(e)
#define SOFT_SCALE 12.984255368000671f
#define LSE_SCALE   8.656170245333781f

typedef __bf16 bf16;
typedef __bf16 bf16x8 __attribute__((ext_vector_type(8)));
typedef __bf16 bf16x4 __attribute__((ext_vector_type(4)));
typedef float  f32x4  __attribute__((ext_vector_type(4)));

// LDS carve (bytes) — 39680 total -> 4 blocks/CU (4*39680 = 158720 <= 163840)
#define OFF_IB    0        // 36*264*2 = 19008 (no pad rows: overlapped tiles {0,16,20})
#define OFF_G     19008    // 36*72*2  = 5184  -> 24192
#define OFF_P     24192    // 4 wave-private: 4*48*40*2 = 15360 -> 39552
#define OFF_GUARD 39552    // 128 B zero tail (sP row-47 pa1 overread)
#define SMEM_TOTAL 39680

#define MFMA16(A,B,C) __builtin_amdgcn_mfma_f32_16x16x32_bf16(A, B, C, 0, 0, 0)

__device__ __forceinline__ float dpp_add16(float v) {
    int x = __builtin_bit_cast(int, v);
    v += __builtin_bit_cast(float, __builtin_amdgcn_update_dpp(0, x, 0xB1, 0xF, 0xF, true));
    x = __builtin_bit_cast(int, v);
    v += __builtin_bit_cast(float, __builtin_amdgcn_update_dpp(0, x, 0x4E, 0xF, 0xF, true));
    x = __builtin_bit_cast(int, v);
    v += __builtin_bit_cast(float, __builtin_amdgcn_update_dpp(0, x, 0x141, 0xF, 0xF, true));
    x = __builtin_bit_cast(int, v);
    v += __builtin_bit_cast(float, __builtin_amdgcn_update_dpp(0, x, 0x140, 0xF, 0xF, true));
    return v;
}

__device__ __forceinline__ float lrelu(float t) { return t > 0.f ? t : 0.1f * t; }

// ---- prep: captions fp32 -> bf16 cache + per-caption-row L2 norms ----
__global__ __launch_bounds__(256)
void prep_kernel(const float* __restrict__ captions, bf16* __restrict__ capb,
                 float* __restrict__ w1g)
{
    const int c = blockIdx.x >> 2, q = blockIdx.x & 3;
    const int wave = threadIdx.x >> 6, lane = threadIdx.x & 63;
    #pragma unroll
    for (int j = 0; j < 3; ++j) {
        int w = q * 12 + wave * 3 + j;
        size_t off = ((size_t)c * NW + w) * ND + lane * 4;
        float4 v = *(const float4*)(captions + off);
        bf16x4 h = { (bf16)v.x, (bf16)v.y, (bf16)v.z, (bf16)v.w };
        *(bf16x4*)(capb + off) = h;
        float s = v.x*v.x + v.y*v.y + v.z*v.z + v.w*v.w;
        s += __shfl_xor(s, 1);  s += __shfl_xor(s, 2);  s += __shfl_xor(s, 4);
        s += __shfl_xor(s, 8);  s += __shfl_xor(s, 16); s += __shfl_xor(s, 32);
        if (lane == 0) w1g[c * NW + w] = sqrtf(s);
    }
}

__device__ __forceinline__ bf16x8 ld_cvt_f32(const float* p, float& ss) {
    float4 lo = *(const float4*)p;
    float4 hi = *(const float4*)(p + 4);
    ss += lo.x*lo.x + lo.y*lo.y + lo.z*lo.z + lo.w*lo.w
        + hi.x*hi.x + hi.y*hi.y + hi.z*hi.z + hi.w*hi.w;
    bf16x8 r = { (bf16)lo.x, (bf16)lo.y, (bf16)lo.z, (bf16)lo.w,
                 (bf16)hi.x, (bf16)hi.y, (bf16)hi.z, (bf16)hi.w };
    return r;
}

// gfx950 unified VGPR/AGPR file: waves_per_eu(4,4) => 128-reg TOTAL budget.
// Demand ~115-120 (no bg hoist, per-mt w1 loads). WRITE_SIZE is the spill canary.
template<bool USE_WS>
__global__ __attribute__((amdgpu_flat_work_group_size(256, 256), amdgpu_waves_per_eu(4, 4)))
void scan_main(const float* __restrict__ images,
               const float* __restrict__ captions,
               const bf16* __restrict__ capb,
               const float* __restrict__ w1g,
               float* __restrict__ out)
{
    __shared__ __align__(16) unsigned char smem[SMEM_TOTAL];
    bf16* sIb = (bf16*)(smem + OFF_IB);   // [r][d] image, 36 real rows only
    bf16* sG  = (bf16*)(smem + OFF_G);    // [r'][r] Gram, 36 rows x 72 cols (36..71 zero)

    const int tid  = threadIdx.x;
    const int wave = tid >> 6;
    const int lane = tid & 63;
    const int quad = lane >> 4;
    const int l15  = lane & 15;
    const int i    = blockIdx.x >> 3;
    const int c0   = (blockIdx.x & 7) * 32;   // chunk == blockIdx%8 -> XCD-pinned captions

    bf16* sPw = (bf16*)(smem + OFF_P) + wave * (48 * PSP);

    // r-tile bases: {0,16,20} — tile 2 overlaps tile 1 on r=20..31; real rows only
    const int rb2 = 20;

    // ---- init: stage image bf16, zero sG and sP+guard ----
    const float* gI = images + (size_t)i * NR * ND;
    #pragma unroll
    for (int k = 0; k < 9; ++k) {
        int t = tid + k * 256;               // 2304 float4
        int e = t * 4, r = e >> 8, d = e & 255;
        float4 v = *(const float4*)(gI + e);
        bf16x4 h = { (bf16)v.x, (bf16)v.y, (bf16)v.z, (bf16)v.w };
        *(bf16x4*)&sIb[r * PIB + d] = h;
    }
    {
        uint32_t* pG = (uint32_t*)sG;        // 1296 dwords
        #pragma unroll
        for (int k = 0; k < 6; ++k) { int x = tid + k * 256; if (x < 1296) pG[x] = 0u; }
        uint32_t* pP = (uint32_t*)(smem + OFF_P);   // sP + guard: 3872 dwords
        #pragma unroll
        for (int k = 0; k < 16; ++k) { int x = tid + k * 256; if (x < 3872) pP[x] = 0u; }
    }
    __syncthreads();   // B0

    // ---- once: Gram G = I*I^T over overlapped m-tiles {0,16,20} (waves 0-2) ----
    if (wave < 3) {
        const int mb = (wave == 2) ? rb2 : wave * 16;
        f32x4 g0 = {0,0,0,0}, g1 = {0,0,0,0}, g2 = {0,0,0,0};
        #pragma unroll
        for (int ks = 0; ks < 8; ++ks) {
            bf16x8 a  = *(const bf16x8*)&sIb[(mb + l15)  * PIB + ks * 32 + quad * 8];
            bf16x8 b0 = *(const bf16x8*)&sIb[(l15)       * PIB + ks * 32 + quad * 8];
            bf16x8 b1 = *(const bf16x8*)&sIb[(16 + l15)  * PIB + ks * 32 + quad * 8];
            bf16x8 b2 = *(const bf16x8*)&sIb[(rb2 + l15) * PIB + ks * 32 + quad * 8];
            g0 = MFMA16(a, b0, g0); g1 = MFMA16(a, b1, g1); g2 = MFMA16(a, b2, g2);
        }
        // duplicate writes in overlap regions carry identical values (benign)
        #pragma unroll
        for (int p = 0; p < 4; ++p) {
            int m = mb + quad * 4 + p;
            sG[m * PG + l15]       = (bf16)g0[p];
            sG[m * PG + 16 + l15]  = (bf16)g1[p];
            sG[m * PG + rb2 + l15] = (bf16)g2[p];
        }
    }
    __syncthreads();   // B1: sG published. No further barriers.

    // ---- per-wave: 8 captions, everything in-wave ----
    for (int it = 0; it < 8; ++it) {
        const int c = c0 + wave * 8 + it;

        // ---- phase 1: raw logits attnT[w][r] = C_c · I^T ----
        f32x4 acc[3][3] = {};
        float ssc[3] = {0.f, 0.f, 0.f};
        float w1f[3][4];                      // !USE_WS only (fallback path)
        const bf16*  ab   = USE_WS ? capb + ((size_t)c * NW + l15) * ND + quad * 8 : nullptr;
        const float* ab32 = USE_WS ? nullptr : captions + ((size_t)c * NW + l15) * ND + quad * 8;
        #pragma unroll
        for (int ks = 0; ks < 8; ++ks) {
            bf16x8 a0, a1, a2;
            if (USE_WS) {
                a0 = *(const bf16x8*)(ab + ks * 32);
                a1 = *(const bf16x8*)(ab + 16 * ND + ks * 32);
                a2 = *(const bf16x8*)(ab + 32 * ND + ks * 32);
            } else {
                a0 = ld_cvt_f32(ab32 + ks * 32, ssc[0]);
                a1 = ld_cvt_f32(ab32 + 16 * ND + ks * 32, ssc[1]);
                a2 = ld_cvt_f32(ab32 + 32 * ND + ks * 32, ssc[2]);
            }
            bf16x8 b0 = *(const bf16x8*)&sIb[(l15)       * PIB + ks * 32 + quad * 8];
            bf16x8 b1 = *(const bf16x8*)&sIb[(16 + l15)  * PIB + ks * 32 + quad * 8];
            bf16x8 b2 = *(const bf16x8*)&sIb[(rb2 + l15) * PIB + ks * 32 + quad * 8];
            acc[0][0] = MFMA16(a0, b0, acc[0][0]);
            acc[1][0] = MFMA16(a1, b0, acc[1][0]);
            acc[2][0] = MFMA16(a2, b0, acc[2][0]);
            acc[0][1] = MFMA16(a0, b1, acc[0][1]);
            acc[1][1] = MFMA16(a1, b1, acc[1][1]);
            acc[2][1] = MFMA16(a2, b1, acc[2][1]);
            acc[0][2] = MFMA16(a0, b2, acc[0][2]);
            acc[1][2] = MFMA16(a1, b2, acc[1][2]);
            acc[2][2] = MFMA16(a2, b2, acc[2][2]);
        }
        if (!USE_WS) {
            #pragma unroll
            for (int mt = 0; mt < 3; ++mt) {
                float s = ssc[mt];
                s += __shfl_xor(s, 16); s += __shfl_xor(s, 32);
                ssc[mt] = sqrtf(s);
            }
            #pragma unroll
            for (int mt = 0; mt < 3; ++mt)
                #pragma unroll
                for (int p = 0; p < 4; ++p)
                    w1f[mt][p] = __shfl(ssc[mt], (lane & 48) + quad * 4 + p);
        }

        // ---- l2norm over w; nt=2 valid at l15>=12 (r=32..35); fold 9*log2e ----
        float inv[3];
        #pragma unroll
        for (int nt = 0; nt < 3; ++nt) {
            float s = 0.f;
            #pragma unroll
            for (int mt = 0; mt < 3; ++mt)
                #pragma unroll
                for (int p = 0; p < 4; ++p) { float t = lrelu(acc[mt][nt][p]); s += t * t; }
            s += __shfl_xor(s, 16); s += __shfl_xor(s, 32);       // sum over w-quads
            inv[nt] = SOFT_SCALE / (sqrtf(s) + 1e-8f);
        }

        // ---- per-mt fused: un-normalized softmax -> sP -> eG MFMA -> w2/rsim/LSE ----
        float esum = 0.f;
        #pragma unroll
        for (int mt = 0; mt < 3; ++mt) {
            // w1 for this mt (L2-hit loads; latency hidden behind the MFMAs below)
            float w1x[4];
            if (USE_WS) {
                #pragma unroll
                for (int p = 0; p < 4; ++p)
                    w1x[p] = w1g[(size_t)c * NW + mt * 16 + quad * 4 + p];
            } else {
                #pragma unroll
                for (int p = 0; p < 4; ++p) w1x[p] = w1f[mt][p];
            }
            float q0[4], q1[4], q2[4], w12v[4];
            #pragma unroll
            for (int p = 0; p < 4; ++p) {
                float e0 = exp2f(lrelu(acc[mt][0][p]) * inv[0]);
                float e1 = exp2f(lrelu(acc[mt][1][p]) * inv[1]);
                float e2 = (l15 >= 12) ? exp2f(lrelu(acc[mt][2][p]) * inv[2]) : 0.f;  // r=32..35
                w12v[p] = dpp_add16(e0 * acc[mt][0][p] + e1 * acc[mt][1][p]
                                   + e2 * acc[mt][2][p]);
                q0[p] = e0; q1[p] = e1; q2[p] = e2;
                int row = mt * 16 + quad * 4 + p;
                sPw[row * PSP + l15]      = (bf16)e0;
                sPw[row * PSP + 16 + l15] = (bf16)e1;
                if (l15 >= 12) sPw[row * PSP + rb2 + l15] = (bf16)e2;   // cols 32..35
            }
            // same-wave RAW on sPw (compiler lgkmcnt); no barrier
            const bf16* ap = &sPw[(mt * 16 + l15) * PSP];
            bf16x8 pa0 = *(const bf16x8*)(ap + quad * 8);
            bf16x8 pa1 = *(const bf16x8*)(ap + 32 + quad * 8);   // overread: finite x sG zeros
            // Gram B-frags reloaded per mt (no hoist: register budget)
            f32x4 pg0 = {0,0,0,0}, pg1 = {0,0,0,0}, pg2 = {0,0,0,0};
            {
                bf16x8 t0 = *(const bf16x8*)&sG[(l15) * PG + quad * 8];
                bf16x8 t1 = *(const bf16x8*)&sG[(l15) * PG + 32 + quad * 8];
                pg0 = MFMA16(pa0, t0, pg0); pg0 = MFMA16(pa1, t1, pg0);
                bf16x8 t2 = *(const bf16x8*)&sG[(16 + l15) * PG + quad * 8];
                bf16x8 t3 = *(const bf16x8*)&sG[(16 + l15) * PG + 32 + quad * 8];
                pg1 = MFMA16(pa0, t2, pg1); pg1 = MFMA16(pa1, t3, pg1);
                bf16x8 t4 = *(const bf16x8*)&sG[(rb2 + l15) * PG + quad * 8];
                bf16x8 t5 = *(const bf16x8*)&sG[(rb2 + l15) * PG + 32 + quad * 8];
                pg2 = MFMA16(pa0, t4, pg2); pg2 = MFMA16(pa1, t5, pg2);
            }
            #pragma unroll
            for (int p = 0; p < 4; ++p) {
                float s2 = pg0[p] * q0[p] + pg1[p] * q1[p] + pg2[p] * q2[p];
                s2 = dpp_add16(s2);
                float w2v = sqrtf(fmaxf(s2, 0.f));
                float rsim = w12v[p] / fmaxf(w1x[p] * w2v, 1e-8f);
                esum += exp2f(LSE_SCALE * rsim);
            }
        }
        esum += __shfl_xor(esum, 16); esum += __shfl_xor(esum, 32);
        if (lane == 0) out[(size_t)i * NC + c] = logf(esum) * (1.0f / 6.0f);
    }
}

extern "C" void kernel_launch(void* const* d_in, const int* in_sizes, int n_in,
                              void* d_out, int out_size, void* d_ws, size_t ws_size,
                              hipStream_t stream) {
    const float* images   = (const float*)d_in[0];   // (128, 36, 256) fp32
    const float* captions = (const float*)d_in[1];   // (256, 48, 256) fp32
    float* out = (float*)d_out;                      // (128, 256) fp32

    const size_t need_w1  = (size_t)NC * NW * sizeof(float);   // 49152
    const size_t need_cap = (size_t)NC * NW * ND * 2;          // 6291456
    bool use_ws = ws_size >= need_w1 + need_cap;

    dim3 grid(1024), block(256);   // 1024 = 256 CU x 4 blocks/CU: single tranche, no tail
    if (use_ws) {
        float* w1g = (float*)d_ws;
        bf16*  capb = (bf16*)((char*)d_ws + need_w1);
        hipLaunchKernelGGL(prep_kernel, dim3(1024), dim3(256), 0, stream, captions, capb, w1g);
        hipLaunchKernelGGL((scan_main<true>), grid, block, 0, stream, images, captions, capb, w1g, out);
    } else {
        hipLaunchKernelGGL((scan_main<false>), grid, block, 0, stream, images, captions,
                           (const bf16*)nullptr, (const float*)nullptr, out);
    }
}

// Round 14
// 170.619 us; speedup vs baseline: 1.4758x; 1.0186x over previous
//
#include <hip/hip_runtime.h>
#include <math.h>

#define NI 128
#define NC 256
#define NR 36
#define NW 48
#define ND 256

#define PIB 264      // sIb pitch (bf16): 528 B rows -> 2-way banks on b128 reads: free
#define PG  72       // sG pitch: 144 B rows, 2-way banks; cols 36..71 stay zero (k-pad)
#define PSP 52       // sP pitch: quad write-offsets {0,8,16,24} banks -> conflict-free writes;
                     // read spans 2-way overlap (free). 16 rows/wave, reused per mt.

// lambda_softmax(9) * log2(e); lambda_lse(6) * log2(e)
#define SOFT_SCALE 12.984255368000671f
#define LSE_SCALE   8.656170245333781f

typedef __bf16 bf16;
typedef __bf16 bf16x8 __attribute__((ext_vector_type(8)));
typedef __bf16 bf16x4 __attribute__((ext_vector_type(4)));
typedef float  f32x4  __attribute__((ext_vector_type(4)));

// LDS carve (bytes) — 30976 total -> 4 blocks/CU
#define OFF_IB    0        // 36*264*2 = 19008 (overlapped r-tiles {0,16,20}, no pad rows)
#define OFF_G     19008    // 36*72*2  = 5184  -> 24192
#define OFF_P     24192    // 4 wave-private: 4*16*52*2 = 6656 -> 30848
#define OFF_GUARD 30848    // 128 B zero tail (row-15 pa1 overread of last wave)
#define SMEM_TOTAL 30976

#define MFMA16(A,B,C) __builtin_amdgcn_mfma_f32_16x16x32_bf16(A, B, C, 0, 0, 0)

__device__ __forceinline__ float dpp_add16(float v) {
    int x = __builtin_bit_cast(int, v);
    v += __builtin_bit_cast(float, __builtin_amdgcn_update_dpp(0, x, 0xB1, 0xF, 0xF, true));
    x = __builtin_bit_cast(int, v);
    v += __builtin_bit_cast(float, __builtin_amdgcn_update_dpp(0, x, 0x4E, 0xF, 0xF, true));
    x = __builtin_bit_cast(int, v);
    v += __builtin_bit_cast(float, __builtin_amdgcn_update_dpp(0, x, 0x141, 0xF, 0xF, true));
    x = __builtin_bit_cast(int, v);
    v += __builtin_bit_cast(float, __builtin_amdgcn_update_dpp(0, x, 0x140, 0xF, 0xF, true));
    return v;
}

__device__ __forceinline__ float lrelu(float t) { return t > 0.f ? t : 0.1f * t; }

// ---- prep: captions fp32 -> bf16 cache + per-caption-row L2 norms ----
__global__ __launch_bounds__(256)
void prep_kernel(const float* __restrict__ captions, bf16* __restrict__ capb,
                 float* __restrict__ w1g)
{
    const int c = blockIdx.x >> 2, q = blockIdx.x & 3;
    const int wave = threadIdx.x >> 6, lane = threadIdx.x & 63;
    #pragma unroll
    for (int j = 0; j < 3; ++j) {
        int w = q * 12 + wave * 3 + j;
        size_t off = ((size_t)c * NW + w) * ND + lane * 4;
        float4 v = *(const float4*)(captions + off);
        bf16x4 h = { (bf16)v.x, (bf16)v.y, (bf16)v.z, (bf16)v.w };
        *(bf16x4*)(capb + off) = h;
        float s = v.x*v.x + v.y*v.y + v.z*v.z + v.w*v.w;
        s += __shfl_xor(s, 1);  s += __shfl_xor(s, 2);  s += __shfl_xor(s, 4);
        s += __shfl_xor(s, 8);  s += __shfl_xor(s, 16); s += __shfl_xor(s, 32);
        if (lane == 0) w1g[c * NW + w] = sqrtf(s);
    }
}

__device__ __forceinline__ bf16x8 ld_cvt_f32(const float* p, float& ss) {
    float4 lo = *(const float4*)p;
    float4 hi = *(const float4*)(p + 4);
    ss += lo.x*lo.x + lo.y*lo.y + lo.z*lo.z + lo.w*lo.w
        + hi.x*hi.x + hi.y*hi.y + hi.z*hi.z + hi.w*hi.w;
    bf16x8 r = { (bf16)lo.x, (bf16)lo.y, (bf16)lo.z, (bf16)lo.w,
                 (bf16)hi.x, (bf16)hi.y, (bf16)hi.z, (bf16)hi.w };
    return r;
}

// gfx950 unified VGPR/AGPR file: waves_per_eu(4,4) => 128-reg TOTAL budget.
// WRITE_SIZE is the spill canary (must stay ~128 KB).
template<bool USE_WS>
__global__ __attribute__((amdgpu_flat_work_group_size(256, 256), amdgpu_waves_per_eu(4, 4)))
void scan_main(const float* __restrict__ images,
               const float* __restrict__ captions,
               const bf16* __restrict__ capb,
               const float* __restrict__ w1g,
               float* __restrict__ out)
{
    __shared__ __align__(16) unsigned char smem[SMEM_TOTAL];
    bf16* sIb = (bf16*)(smem + OFF_IB);   // [r][d] image, 36 real rows only
    bf16* sG  = (bf16*)(smem + OFF_G);    // [r'][r] Gram, 36 rows x 72 cols (36..71 zero)

    const int tid  = threadIdx.x;
    const int wave = tid >> 6;
    const int lane = tid & 63;
    const int quad = lane >> 4;
    const int l15  = lane & 15;
    const int i    = blockIdx.x >> 3;
    const int c0   = (blockIdx.x & 7) * 32;   // chunk == blockIdx%8 -> XCD-pinned captions

    bf16* sPw = (bf16*)(smem + OFF_P) + wave * (16 * PSP);   // 16-row buffer, reused per mt

    // r-tile bases: {0,16,20} — tile 2 overlaps tile 1 on r=20..31; real rows only
    const int rb2 = 20;

    // ---- init: stage image bf16, zero sG and sP+guard ----
    const float* gI = images + (size_t)i * NR * ND;
    #pragma unroll
    for (int k = 0; k < 9; ++k) {
        int t = tid + k * 256;               // 2304 float4
        int e = t * 4, r = e >> 8, d = e & 255;
        float4 v = *(const float4*)(gI + e);
        bf16x4 h = { (bf16)v.x, (bf16)v.y, (bf16)v.z, (bf16)v.w };
        *(bf16x4*)&sIb[r * PIB + d] = h;
    }
    {
        uint32_t* pG = (uint32_t*)sG;        // 1296 dwords
        #pragma unroll
        for (int k = 0; k < 6; ++k) { int x = tid + k * 256; if (x < 1296) pG[x] = 0u; }
        uint32_t* pP = (uint32_t*)(smem + OFF_P);   // sP + guard: 1696 dwords
        #pragma unroll
        for (int k = 0; k < 7; ++k) { int x = tid + k * 256; if (x < 1696) pP[x] = 0u; }
        // cols 36..51 of each sP row are never written after this -> stay zero (k-pad safety)
    }
    __syncthreads();   // B0

    // ---- once: Gram G = I*I^T over overlapped m-tiles {0,16,20} (waves 0-2) ----
    if (wave < 3) {
        const int mb = (wave == 2) ? rb2 : wave * 16;
        f32x4 g0 = {0,0,0,0}, g1 = {0,0,0,0}, g2 = {0,0,0,0};
        #pragma unroll
        for (int ks = 0; ks < 8; ++ks) {
            bf16x8 a  = *(const bf16x8*)&sIb[(mb + l15)  * PIB + ks * 32 + quad * 8];
            bf16x8 b0 = *(const bf16x8*)&sIb[(l15)       * PIB + ks * 32 + quad * 8];
            bf16x8 b1 = *(const bf16x8*)&sIb[(16 + l15)  * PIB + ks * 32 + quad * 8];
            bf16x8 b2 = *(const bf16x8*)&sIb[(rb2 + l15) * PIB + ks * 32 + quad * 8];
            g0 = MFMA16(a, b0, g0); g1 = MFMA16(a, b1, g1); g2 = MFMA16(a, b2, g2);
        }
        // duplicate writes in overlap regions carry identical values (benign)
        #pragma unroll
        for (int p = 0; p < 4; ++p) {
            int m = mb + quad * 4 + p;
            sG[m * PG + l15]       = (bf16)g0[p];
            sG[m * PG + 16 + l15]  = (bf16)g1[p];
            sG[m * PG + rb2 + l15] = (bf16)g2[p];
        }
    }
    __syncthreads();   // B1: sG published. No further barriers.

    // ---- per-wave: 8 captions, everything in-wave ----
    for (int it = 0; it < 8; ++it) {
        const int c = c0 + wave * 8 + it;

        // ---- phase 1: raw logits attnT[w][r] = C_c · I^T ----
        f32x4 acc[3][3] = {};
        float ssc[3] = {0.f, 0.f, 0.f};
        float w1f[3][4];                      // !USE_WS only (fallback path)
        const bf16*  ab   = USE_WS ? capb + ((size_t)c * NW + l15) * ND + quad * 8 : nullptr;
        const float* ab32 = USE_WS ? nullptr : captions + ((size_t)c * NW + l15) * ND + quad * 8;
        #pragma unroll
        for (int ks = 0; ks < 8; ++ks) {
            bf16x8 a0, a1, a2;
            if (USE_WS) {
                a0 = *(const bf16x8*)(ab + ks * 32);
                a1 = *(const bf16x8*)(ab + 16 * ND + ks * 32);
                a2 = *(const bf16x8*)(ab + 32 * ND + ks * 32);
            } else {
                a0 = ld_cvt_f32(ab32 + ks * 32, ssc[0]);
                a1 = ld_cvt_f32(ab32 + 16 * ND + ks * 32, ssc[1]);
                a2 = ld_cvt_f32(ab32 + 32 * ND + ks * 32, ssc[2]);
            }
            bf16x8 b0 = *(const bf16x8*)&sIb[(l15)       * PIB + ks * 32 + quad * 8];
            bf16x8 b1 = *(const bf16x8*)&sIb[(16 + l15)  * PIB + ks * 32 + quad * 8];
            bf16x8 b2 = *(const bf16x8*)&sIb[(rb2 + l15) * PIB + ks * 32 + quad * 8];
            acc[0][0] = MFMA16(a0, b0, acc[0][0]);
            acc[1][0] = MFMA16(a1, b0, acc[1][0]);
            acc[2][0] = MFMA16(a2, b0, acc[2][0]);
            acc[0][1] = MFMA16(a0, b1, acc[0][1]);
            acc[1][1] = MFMA16(a1, b1, acc[1][1]);
            acc[2][1] = MFMA16(a2, b1, acc[2][1]);
            acc[0][2] = MFMA16(a0, b2, acc[0][2]);
            acc[1][2] = MFMA16(a1, b2, acc[1][2]);
            acc[2][2] = MFMA16(a2, b2, acc[2][2]);
        }
        if (!USE_WS) {
            #pragma unroll
            for (int mt = 0; mt < 3; ++mt) {
                float s = ssc[mt];
                s += __shfl_xor(s, 16); s += __shfl_xor(s, 32);
                ssc[mt] = sqrtf(s);
            }
            #pragma unroll
            for (int mt = 0; mt < 3; ++mt)
                #pragma unroll
                for (int p = 0; p < 4; ++p)
                    w1f[mt][p] = __shfl(ssc[mt], (lane & 48) + quad * 4 + p);
        }

        // ---- l2norm over w; nt=2 valid at l15>=12 (r=32..35); fold 9*log2e ----
        float inv[3];
        #pragma unroll
        for (int nt = 0; nt < 3; ++nt) {
            float s = 0.f;
            #pragma unroll
            for (int mt = 0; mt < 3; ++mt)
                #pragma unroll
                for (int p = 0; p < 4; ++p) { float t = lrelu(acc[mt][nt][p]); s += t * t; }
            s += __shfl_xor(s, 16); s += __shfl_xor(s, 32);       // sum over w-quads
            inv[nt] = SOFT_SCALE * __frsqrt_rn(fmaxf(s, 1e-12f));
        }

        // ---- per-mt fused: un-normalized softmax -> sP(16-row buf) -> eG MFMA -> epilogue ----
        float esum = 0.f;
        #pragma unroll
        for (int mt = 0; mt < 3; ++mt) {
            float w1x[4];
            if (USE_WS) {
                #pragma unroll
                for (int p = 0; p < 4; ++p)
                    w1x[p] = w1g[(size_t)c * NW + mt * 16 + quad * 4 + p];
            } else {
                #pragma unroll
                for (int p = 0; p < 4; ++p) w1x[p] = w1f[mt][p];
            }
            float q0[4], q1[4], q2[4], w12v[4];
            #pragma unroll
            for (int p = 0; p < 4; ++p) {
                float e0 = exp2f(lrelu(acc[mt][0][p]) * inv[0]);
                float e1 = exp2f(lrelu(acc[mt][1][p]) * inv[1]);
                float e2 = (l15 >= 12) ? exp2f(lrelu(acc[mt][2][p]) * inv[2]) : 0.f;  // r=32..35
                w12v[p] = dpp_add16(e0 * acc[mt][0][p] + e1 * acc[mt][1][p]
                                   + e2 * acc[mt][2][p]);
                q0[p] = e0; q1[p] = e1; q2[p] = e2;
                int row = quad * 4 + p;                 // buffer-local row (reused per mt)
                sPw[row * PSP + l15]      = (bf16)e0;
                sPw[row * PSP + 16 + l15] = (bf16)e1;
                if (l15 >= 12) sPw[row * PSP + rb2 + l15] = (bf16)e2;   // cols 32..35
            }
            // same-wave RAW on sPw (compiler lgkmcnt); no barrier
            const bf16* ap = &sPw[l15 * PSP];
            bf16x8 pa0 = *(const bf16x8*)(ap + quad * 8);
            bf16x8 pa1 = *(const bf16x8*)(ap + 32 + quad * 8);   // cols 36..51 zero; >=52 finite x G-zeros
            f32x4 pg0 = {0,0,0,0}, pg1 = {0,0,0,0}, pg2 = {0,0,0,0};
            {
                bf16x8 t0 = *(const bf16x8*)&sG[(l15) * PG + quad * 8];
                bf16x8 t1 = *(const bf16x8*)&sG[(l15) * PG + 32 + quad * 8];
                pg0 = MFMA16(pa0, t0, pg0); pg0 = MFMA16(pa1, t1, pg0);
                bf16x8 t2 = *(const bf16x8*)&sG[(16 + l15) * PG + quad * 8];
                bf16x8 t3 = *(const bf16x8*)&sG[(16 + l15) * PG + 32 + quad * 8];
                pg1 = MFMA16(pa0, t2, pg1); pg1 = MFMA16(pa1, t3, pg1);
                bf16x8 t4 = *(const bf16x8*)&sG[(rb2 + l15) * PG + quad * 8];
                bf16x8 t5 = *(const bf16x8*)&sG[(rb2 + l15) * PG + 32 + quad * 8];
                pg2 = MFMA16(pa0, t4, pg2); pg2 = MFMA16(pa1, t5, pg2);
            }
            #pragma unroll
            for (int p = 0; p < 4; ++p) {
                float s2 = pg0[p] * q0[p] + pg1[p] * q1[p] + pg2[p] * q2[p];
                s2 = dpp_add16(s2);
                // rsim = w12 / (w1 * sqrt(s2)) via rsqrt+rcp (1-ulp, within tolerance)
                float rsim = w12v[p] * __frsqrt_rn(fmaxf(s2, 1e-16f)) * __frcp_rn(w1x[p]);
                esum += exp2f(LSE_SCALE * rsim);
            }
        }
        esum += __shfl_xor(esum, 16); esum += __shfl_xor(esum, 32);
        if (lane == 0) out[(size_t)i * NC + c] = logf(esum) * (1.0f / 6.0f);
    }
}

extern "C" void kernel_launch(void* const* d_in, const int* in_sizes, int n_in,
                              void* d_out, int out_size, void* d_ws, size_t ws_size,
                              hipStream_t stream) {
    const float* images   = (const float*)d_in[0];   // (128, 36, 256) fp32
    const float* captions = (const float*)d_in[1];   // (256, 48, 256) fp32
    float* out = (float*)d_out;                      // (128, 256) fp32

    const size_t need_w1  = (size_t)NC * NW * sizeof(float);   // 49152
    const size_t need_cap = (size_t)NC * NW * ND * 2;          // 6291456
    bool use_ws = ws_size >= need_w1 + need_cap;

    dim3 grid(1024), block(256);   // 1024 = 256 CU x 4 blocks/CU: single tranche, no tail
    if (use_ws) {
        float* w1g = (float*)d_ws;
        bf16*  capb = (bf16*)((char*)d_ws + need_w1);
        hipLaunchKernelGGL(prep_kernel, dim3(1024), dim3(256), 0, stream, captions, capb, w1g);
        hipLaunchKernelGGL((scan_main<true>), grid, block, 0, stream, images, captions, capb, w1g, out);
    } else {
        hipLaunchKernelGGL((scan_main<false>), grid, block, 0, stream, images, captions,
                           (const bf16*)nullptr, (const float*)nullptr, out);
    }
}